// Round 6
// baseline (73.007 us; speedup 1.0000x reference)
//
#include <hip/hip_runtime.h>

#define LN_EPS 1e-5f
#define DD 128
#define TWO_D 256
#define HH 64

typedef unsigned int uint;
typedef __attribute__((ext_vector_type(8))) short short8v;   // 8 bf16 (4 VGPRs)
typedef __attribute__((ext_vector_type(4))) float f32x4;     // MFMA accumulator

__device__ __forceinline__ unsigned short f2bf(float f) {
    uint u = __float_as_uint(f);
    u += 0x7FFFu + ((u >> 16) & 1u);  // round-to-nearest-even
    return (unsigned short)(u >> 16);
}
__device__ __forceinline__ float bf2f(unsigned short h) {
    return __uint_as_float(((uint)h) << 16);
}

// ---------------- fused: block 0 = prep (G, B1c); blocks [1,nbN] = node proj;
// blocks (nbN, nbN+nbE] = edge proj. Each proj block: 128 rows via MFMA.
__global__ __launch_bounds__(256) void k_fused(
    const float* __restrict__ node_feat, int n_nodes, int nbN,
    const float* __restrict__ edge_feat, int n_edges,
    const float* __restrict__ gamma, const float* __restrict__ beta,
    const float* __restrict__ W1, const float* __restrict__ b1,
    unsigned short* __restrict__ node_pt, float2* __restrict__ node_sums,
    unsigned short* __restrict__ edge_pt, float2* __restrict__ edge_sums,
    float* __restrict__ GB) {
    int bid = blockIdx.x;
    int tid = threadIdx.x;

    if (bid == 0) {
        if (tid < 128) {
            int h = tid & 63;
            bool isB = tid >= 64;
            float acc = isB ? b1[h] : 0.f;
            const float* coef = isB ? beta : gamma;
#pragma unroll 8
            for (int d = 0; d < TWO_D; ++d)
                acc = fmaf(coef[d], W1[d * HH + h], acc);
            GB[tid] = acc;
        }
        return;
    }

    const float* feat;
    int nrows, gofs, rbase0;
    unsigned short* pt;
    float2* sums;
    if (bid <= nbN) {
        feat = node_feat; nrows = n_nodes; gofs = 128;
        rbase0 = (bid - 1) * 128; pt = node_pt; sums = node_sums;
    } else {
        feat = edge_feat; nrows = n_edges; gofs = 0;
        rbase0 = (bid - 1 - nbN) * 128; pt = edge_pt; sums = edge_sums;
    }

    __shared__ __align__(16) char lds[49152];

    // ---- stage gwB in MFMA B-fragment order: B[k][h] = gamma[gofs+k]*W1[gofs+k][h]
    {
        int l = tid & 63;
        int w = tid >> 6;  // 0..3
#pragma unroll
        for (int ci = 0; ci < 4; ++ci) {
            int combo = ci * 4 + w;           // = ht*4 + ks
            int ks = combo & 3;
            int ht = combo >> 2;
            int kbase = gofs + ks * 32 + (l >> 4) * 8;
            int h = ht * 16 + (l & 15);
            unsigned short vals[8];
#pragma unroll
            for (int j = 0; j < 8; ++j)
                vals[j] = f2bf(gamma[kbase + j] * W1[(size_t)(kbase + j) * HH + h]);
            short8v v;
#pragma unroll
            for (int j = 0; j < 8; ++j) v[j] = (short)vals[j];
            *(short8v*)(lds + 32768 + combo * 1024 + l * 16) = v;
        }
    }

    // ---- stage featA: 64KB contiguous f32 -> bf16 LDS tile (burst of 16 dwordx4)
    {
        float4 tmp[16];
#pragma unroll
        for (int u = 0; u < 16; ++u) {
            int F4 = u * 256 + tid;        // float4 index within tile
            int r = F4 >> 5;               // 32 float4 per row
            int rg = rbase0 + r;
            rg = rg < nrows ? rg : (nrows - 1);
            int c4 = (F4 & 31) * 4;        // col in floats
            tmp[u] = *(const float4*)&feat[(size_t)rg * DD + c4];
        }
#pragma unroll
        for (int u = 0; u < 16; ++u) {
            int F4 = u * 256 + tid;
            int r = F4 >> 5;
            int c4 = (F4 & 31) * 4;
            uint2 wv;
            wv.x = (uint)f2bf(tmp[u].x) | ((uint)f2bf(tmp[u].y) << 16);
            wv.y = (uint)f2bf(tmp[u].z) | ((uint)f2bf(tmp[u].w) << 16);
            int byte = (r * 256 + c4 * 2) ^ ((r & 7) << 4);
            *(uint2*)(lds + byte) = wv;
        }
    }

    __syncthreads();

    // ---- MFMA: wave w computes rows [32w, 32w+32) x 64 h
    int w = tid >> 6;
    int lane = tid & 63;
    f32x4 acc[2][4];
#pragma unroll
    for (int i = 0; i < 2; ++i)
#pragma unroll
        for (int j = 0; j < 4; ++j) acc[i][j] = (f32x4){0.f, 0.f, 0.f, 0.f};

    int arow_lo = lane & 15;
    int akofs = (lane >> 4) * 8;
#pragma unroll
    for (int ks = 0; ks < 4; ++ks) {
        int kk = ks * 32 + akofs;
        int rr0 = (2 * w) * 16 + arow_lo;
        int rr1 = rr0 + 16;
        short8v a0 = *(const short8v*)(lds + ((rr0 * 256 + kk * 2) ^ ((rr0 & 7) << 4)));
        short8v a1 = *(const short8v*)(lds + ((rr1 * 256 + kk * 2) ^ ((rr1 & 7) << 4)));
#pragma unroll
        for (int ht = 0; ht < 4; ++ht) {
            short8v b = *(const short8v*)(lds + 32768 + (ht * 4 + ks) * 1024 + lane * 16);
            acc[0][ht] = __builtin_amdgcn_mfma_f32_16x16x32_bf16(a0, b, acc[0][ht], 0, 0, 0);
            acc[1][ht] = __builtin_amdgcn_mfma_f32_16x16x32_bf16(a1, b, acc[1][ht], 0, 0, 0);
        }
    }

    // ---- sums from LDS bf16 tile (2 threads per row)
    {
        int row = tid >> 1, half = tid & 1;
        float s = 0.f, q = 0.f;
#pragma unroll
        for (int i = 0; i < 8; ++i) {
            int byte = (row * 256 + half * 128 + i * 16) ^ ((row & 7) << 4);
            short8v v = *(const short8v*)(lds + byte);
#pragma unroll
            for (int j = 0; j < 8; ++j) {
                float x = bf2f((unsigned short)v[j]);
                s += x;
                q = fmaf(x, x, q);
            }
        }
        s += __shfl_xor(s, 1);
        q += __shfl_xor(q, 1);
        if (half == 0 && rbase0 + row < nrows) sums[rbase0 + row] = make_float2(s, q);
    }

    __syncthreads();  // all waves done reading gwB before overwrite

    // ---- epilogue: acc -> outB (LDS, reusing gwB space), then coalesced store
    {
        unsigned short* ob = (unsigned short*)(lds + 32768);
        int colh = lane & 15;
        int rquad = lane >> 4;
#pragma unroll
        for (int rt = 0; rt < 2; ++rt)
#pragma unroll
            for (int ht = 0; ht < 4; ++ht)
#pragma unroll
                for (int reg = 0; reg < 4; ++reg) {
                    int r = (2 * w + rt) * 16 + rquad * 4 + reg;
                    int h = ht * 16 + colh;
                    ob[r * 64 + h] = f2bf(acc[rt][ht][reg]);
                }
        int row = tid >> 1;
        if (rbase0 + row < nrows) {
#pragma unroll
            for (int i = 0; i < 4; ++i) {
                short8v v = *(const short8v*)(lds + 32768 + tid * 64 + i * 16);
                *(short8v*)&pt[(size_t)rbase0 * HH + tid * 32 + i * 8] = v;
            }
        }
    }
}

// ---------------- zero the 8 bucket counters
__global__ void k_zero8(uint* gcnt) { gcnt[threadIdx.x] = 0; }

// ---------------- bin pairs into 8 buckets by node-index slice (XCD locality)
// One block = one contiguous chunk of pairs. Pass1: LDS histogram; range-reserve
// via 8 global atomics; pass2: scatter packed records {ni|(ei<<17), p}.
__global__ __launch_bounds__(256) void k_bin(const int* __restrict__ node_idx,
                                             const int* __restrict__ edge_idx,
                                             int E, float scale, uint* __restrict__ gcnt,
                                             uint2* __restrict__ binned, int Ecap) {
    __shared__ uint lc[8];
    __shared__ uint lofs[8];
    int tid = threadIdx.x;
    if (tid < 8) lc[tid] = 0;
    __syncthreads();
    int per = (E + (int)gridDim.x - 1) / (int)gridDim.x;
    int s = blockIdx.x * per;
    int e = s + per < E ? s + per : E;
    for (int p = s + tid; p < e; p += 256) {
        int b = (int)((float)node_idx[p] * scale);
        b = b < 7 ? b : 7;
        atomicAdd(&lc[b], 1u);
    }
    __syncthreads();
    if (tid < 8) lofs[tid] = atomicAdd(&gcnt[tid], lc[tid]);
    __syncthreads();
    for (int p = s + tid; p < e; p += 256) {
        int ni = node_idx[p];
        int ei = edge_idx[p];
        int b = (int)((float)ni * scale);
        b = b < 7 ? b : 7;
        uint pos = atomicAdd(&lofs[b], 1u);
        binned[(size_t)b * Ecap + pos] = make_uint2((uint)ni | ((uint)ei << 17), (uint)p);
    }
}

// ---------------- per-pair fused LN+MLP, bucket-binned for XCD-L2 locality.
// bucket = blockIdx%8 (matches round-robin block->XCD); 8 lanes per pair.
__global__ __launch_bounds__(256) void k_pairs_b(const uint2* __restrict__ binned, int Ecap,
                                                 const uint* __restrict__ gcnt,
                                                 const unsigned short* __restrict__ node_pt,
                                                 const unsigned short* __restrict__ edge_pt,
                                                 const float2* __restrict__ node_sums,
                                                 const float2* __restrict__ edge_sums,
                                                 const float* __restrict__ Gv,
                                                 const float* __restrict__ Bv,
                                                 const float* __restrict__ W2,
                                                 const float* __restrict__ b2,
                                                 float* __restrict__ out) {
    int bucket = blockIdx.x & 7;
    int nchunk = (int)gridDim.x >> 3;
    int chunk = blockIdx.x >> 3;
    uint sz = gcnt[bucket];
    uint per = (sz + nchunk - 1) / nchunk;
    uint beg = chunk * per;
    uint end = beg + per < sz ? beg + per : sz;
    const uint2* bb = binned + (size_t)bucket * Ecap;

    int tid = threadIdx.x;
    int l = tid & 7;
    int grp = tid >> 3;  // 32 groups/block

    float G8[8], B8[8], W8[8];
#pragma unroll
    for (int j = 0; j < 8; ++j) {
        G8[j] = Gv[l * 8 + j];
        B8[j] = Bv[l * 8 + j];
        W8[j] = W2[l * 8 + j];
    }
    float b2v = b2[0];

#pragma unroll 2
    for (uint i = beg + grp; i < end; i += 32) {
        uint2 rec = bb[i];
        uint ni = rec.x & 0x1FFFFu;
        uint ei = rec.x >> 17;
        uint4 ue = *(const uint4*)&edge_pt[(size_t)ei * HH + l * 8];
        uint4 un = *(const uint4*)&node_pt[(size_t)ni * HH + l * 8];
        float2 se = edge_sums[ei];
        float2 sn = node_sums[ni];

        float S = se.x + sn.x;
        float Q = se.y + sn.y;
        float mu = S * (1.f / TWO_D);
        float var = fmaf(Q, 1.f / TWO_D, -mu * mu);
        float rstd = rsqrtf(var + LN_EPS);
        float nmu = -mu;

        uint ue_[4] = {ue.x, ue.y, ue.z, ue.w};
        uint un_[4] = {un.x, un.y, un.z, un.w};
        float acc = 0.f;
#pragma unroll
        for (int j = 0; j < 4; ++j) {
            float pe0 = __uint_as_float(ue_[j] << 16);
            float pe1 = __uint_as_float(ue_[j] & 0xFFFF0000u);
            float pn0 = __uint_as_float(un_[j] << 16);
            float pn1 = __uint_as_float(un_[j] & 0xFFFF0000u);
            float t0 = fmaf(nmu, G8[2 * j], pe0 + pn0);
            float v0 = fmaf(rstd, t0, B8[2 * j]);
            v0 = fmaxf(v0, 0.f);
            acc = fmaf(v0, W8[2 * j], acc);
            float t1 = fmaf(nmu, G8[2 * j + 1], pe1 + pn1);
            float v1 = fmaf(rstd, t1, B8[2 * j + 1]);
            v1 = fmaxf(v1, 0.f);
            acc = fmaf(v1, W8[2 * j + 1], acc);
        }

        acc += __shfl_xor(acc, 1);
        acc += __shfl_xor(acc, 2);
        acc += __shfl_xor(acc, 4);

        if (l == 0) out[rec.y] = acc + b2v;
    }
}

// ---------------- fallback unbinned pairs (if packing/ws guard fails)
__global__ __launch_bounds__(256) void k_pairs(const int* __restrict__ node_idx,
                                               const int* __restrict__ edge_idx,
                                               const unsigned short* __restrict__ node_pt,
                                               const unsigned short* __restrict__ edge_pt,
                                               const float2* __restrict__ node_sums,
                                               const float2* __restrict__ edge_sums,
                                               const float* __restrict__ Gv,
                                               const float* __restrict__ Bv,
                                               const float* __restrict__ W2,
                                               const float* __restrict__ b2,
                                               float* __restrict__ out, int E) {
    int gtid = blockIdx.x * 256 + threadIdx.x;
    int l = gtid & 7;
    int grp = gtid >> 3;
    int ngrps = (gridDim.x * 256) >> 3;

    float G8[8], B8[8], W8[8];
#pragma unroll
    for (int j = 0; j < 8; ++j) {
        G8[j] = Gv[l * 8 + j];
        B8[j] = Bv[l * 8 + j];
        W8[j] = W2[l * 8 + j];
    }
    float b2v = b2[0];

#pragma unroll 2
    for (int p = grp; p < E; p += ngrps) {
        int ni = node_idx[p];
        int ei = edge_idx[p];
        uint4 ue = *(const uint4*)&edge_pt[(size_t)ei * HH + l * 8];
        uint4 un = *(const uint4*)&node_pt[(size_t)ni * HH + l * 8];
        float2 se = edge_sums[ei];
        float2 sn = node_sums[ni];

        float S = se.x + sn.x;
        float Q = se.y + sn.y;
        float mu = S * (1.f / TWO_D);
        float var = fmaf(Q, 1.f / TWO_D, -mu * mu);
        float rstd = rsqrtf(var + LN_EPS);
        float nmu = -mu;

        uint ue_[4] = {ue.x, ue.y, ue.z, ue.w};
        uint un_[4] = {un.x, un.y, un.z, un.w};
        float acc = 0.f;
#pragma unroll
        for (int j = 0; j < 4; ++j) {
            float pe0 = __uint_as_float(ue_[j] << 16);
            float pe1 = __uint_as_float(ue_[j] & 0xFFFF0000u);
            float pn0 = __uint_as_float(un_[j] << 16);
            float pn1 = __uint_as_float(un_[j] & 0xFFFF0000u);
            float t0 = fmaf(nmu, G8[2 * j], pe0 + pn0);
            float v0 = fmaf(rstd, t0, B8[2 * j]);
            v0 = fmaxf(v0, 0.f);
            acc = fmaf(v0, W8[2 * j], acc);
            float t1 = fmaf(nmu, G8[2 * j + 1], pe1 + pn1);
            float v1 = fmaf(rstd, t1, B8[2 * j + 1]);
            v1 = fmaxf(v1, 0.f);
            acc = fmaf(v1, W8[2 * j + 1], acc);
        }

        acc += __shfl_xor(acc, 1);
        acc += __shfl_xor(acc, 2);
        acc += __shfl_xor(acc, 4);

        if (l == 0) out[p] = acc + b2v;
    }
}

extern "C" void kernel_launch(void* const* d_in, const int* in_sizes, int n_in,
                              void* d_out, int out_size, void* d_ws, size_t ws_size,
                              hipStream_t stream) {
    const float* node_feat = (const float*)d_in[0];
    const float* edge_feat = (const float*)d_in[1];
    const float* gamma = (const float*)d_in[2];
    const float* beta = (const float*)d_in[3];
    const float* W1 = (const float*)d_in[4];
    const float* b1 = (const float*)d_in[5];
    const float* W2 = (const float*)d_in[6];
    const float* b2 = (const float*)d_in[7];
    const int* node_idx = (const int*)d_in[8];
    const int* edge_idx = (const int*)d_in[9];

    int n_nodes = in_sizes[0] / DD;
    int n_edges = in_sizes[1] / DD;
    int E = in_sizes[8];

    char* wsb = (char*)d_ws;
    size_t o = 0;
    float* GB = (float*)(wsb + o); o += 512;
    float2* node_sums = (float2*)(wsb + o); o += (size_t)n_nodes * 8;
    float2* edge_sums = (float2*)(wsb + o); o += (size_t)n_edges * 8;
    o = (o + 127) & ~(size_t)127;
    unsigned short* node_pt = (unsigned short*)(wsb + o); o += (size_t)n_nodes * HH * 2;
    unsigned short* edge_pt = (unsigned short*)(wsb + o); o += (size_t)n_edges * HH * 2;
    o = (o + 127) & ~(size_t)127;
    uint* gcnt = (uint*)(wsb + o); o += 128;
    uint2* binned = (uint2*)(wsb + o);
    size_t need = o + (size_t)8 * (size_t)E * sizeof(uint2);

    bool can_bin = (n_nodes <= (1 << 17)) && (n_edges <= (1 << 15)) && (ws_size >= need);

    int nbN = (n_nodes + 127) / 128;
    int nbE = (n_edges + 127) / 128;

    if (can_bin) {
        float scale = 8.0f / (float)n_nodes;
        k_zero8<<<1, 8, 0, stream>>>(gcnt);
        k_bin<<<256, 256, 0, stream>>>(node_idx, edge_idx, E, scale, gcnt, binned, E);
    }

    k_fused<<<1 + nbN + nbE, 256, 0, stream>>>(node_feat, n_nodes, nbN,
                                               edge_feat, n_edges,
                                               gamma, beta, W1, b1,
                                               node_pt, node_sums,
                                               edge_pt, edge_sums, GB);

    if (can_bin) {
        k_pairs_b<<<2048, 256, 0, stream>>>(binned, E, gcnt, node_pt, edge_pt,
                                            node_sums, edge_sums, GB, GB + 64, W2, b2,
                                            (float*)d_out);
    } else {
        k_pairs<<<2048, 256, 0, stream>>>(node_idx, edge_idx, node_pt, edge_pt,
                                          node_sums, edge_sums, GB, GB + 64, W2, b2,
                                          (float*)d_out, E);
    }
}

// Round 8
// 54.359 us; speedup vs baseline: 1.3431x; 1.3431x over previous
//
#include <hip/hip_runtime.h>

#define LN_EPS 1e-5f
#define DD 128
#define TWO_D 256
#define HH 64

typedef unsigned int uint;
typedef __attribute__((ext_vector_type(8))) short short8v;   // 8 bf16 (4 VGPRs)
typedef __attribute__((ext_vector_type(4))) float f32x4;     // MFMA accumulator

__device__ __forceinline__ unsigned short f2bf(float f) {
    uint u = __float_as_uint(f);
    u += 0x7FFFu + ((u >> 16) & 1u);  // round-to-nearest-even
    return (unsigned short)(u >> 16);
}
__device__ __forceinline__ float bf2f(unsigned short h) {
    return __uint_as_float(((uint)h) << 16);
}

// ---------------- fused: block 0 = prep (G, B1c); blocks [1,nbN] = node proj;
// blocks (nbN, nbN+nbE] = edge proj. Each proj block: 128 rows via MFMA,
// output int8-quantized per row (scale in stats.z), h-permuted byte layout:
// table byte b of a row holds h = (b&3)*16 + (b>>2).
// stats[r] = (S, Q, scale_dq, 0)
__global__ __launch_bounds__(256) void k_fused(
    const float* __restrict__ node_feat, int n_nodes, int nbN,
    const float* __restrict__ edge_feat, int n_edges,
    const float* __restrict__ gamma, const float* __restrict__ beta,
    const float* __restrict__ W1, const float* __restrict__ b1,
    signed char* __restrict__ node_pt, float4* __restrict__ node_st,
    signed char* __restrict__ edge_pt, float4* __restrict__ edge_st,
    float* __restrict__ GB) {
    int bid = blockIdx.x;
    int tid = threadIdx.x;

    if (bid == 0) {
        if (tid < 128) {
            int h = tid & 63;
            bool isB = tid >= 64;
            float acc = isB ? b1[h] : 0.f;
            const float* coef = isB ? beta : gamma;
#pragma unroll 8
            for (int d = 0; d < TWO_D; ++d)
                acc = fmaf(coef[d], W1[d * HH + h], acc);
            GB[tid] = acc;
        }
        return;
    }

    const float* feat;
    int nrows, gofs, rbase0;
    signed char* pt;
    float4* st;
    if (bid <= nbN) {
        feat = node_feat; nrows = n_nodes; gofs = 128;
        rbase0 = (bid - 1) * 128; pt = node_pt; st = node_st;
    } else {
        feat = edge_feat; nrows = n_edges; gofs = 0;
        rbase0 = (bid - 1 - nbN) * 128; pt = edge_pt; st = edge_st;
    }

    // LDS: [0,32K) featA bf16 [128][128], byte=(r*256+k*2)^((r&7)<<4)
    //      [32K,48K) gwB packed MFMA-B frags
    //      [48K,48K+512) per-row scale
    __shared__ __align__(16) char lds[49664];
    float* scaleLDS = (float*)(lds + 49152);

    // ---- stage gwB in MFMA B-fragment order: B[k][h] = gamma[gofs+k]*W1[gofs+k][h]
    {
        int l = tid & 63;
        int w = tid >> 6;  // 0..3
#pragma unroll
        for (int ci = 0; ci < 4; ++ci) {
            int combo = ci * 4 + w;           // = ht*4 + ks
            int ks = combo & 3;
            int ht = combo >> 2;
            int kbase = gofs + ks * 32 + (l >> 4) * 8;
            int h = ht * 16 + (l & 15);
            short8v v;
#pragma unroll
            for (int j = 0; j < 8; ++j)
                v[j] = (short)f2bf(gamma[kbase + j] * W1[(size_t)(kbase + j) * HH + h]);
            *(short8v*)(lds + 32768 + combo * 1024 + l * 16) = v;
        }
    }

    // ---- stage featA: 64KB contiguous f32 -> bf16 LDS tile (burst of 16 dwordx4)
    {
        float4 tmp[16];
#pragma unroll
        for (int u = 0; u < 16; ++u) {
            int F4 = u * 256 + tid;        // float4 index within tile
            int r = F4 >> 5;               // 32 float4 per row
            int rg = rbase0 + r;
            rg = rg < nrows ? rg : (nrows - 1);
            int c4 = (F4 & 31) * 4;        // col in floats
            tmp[u] = *(const float4*)&feat[(size_t)rg * DD + c4];
        }
#pragma unroll
        for (int u = 0; u < 16; ++u) {
            int F4 = u * 256 + tid;
            int r = F4 >> 5;
            int c4 = (F4 & 31) * 4;
            uint2 wv;
            wv.x = (uint)f2bf(tmp[u].x) | ((uint)f2bf(tmp[u].y) << 16);
            wv.y = (uint)f2bf(tmp[u].z) | ((uint)f2bf(tmp[u].w) << 16);
            int byte = (r * 256 + c4 * 2) ^ ((r & 7) << 4);
            *(uint2*)(lds + byte) = wv;
        }
    }

    __syncthreads();

    // ---- MFMA: wave w computes rows [32w, 32w+32) x 64 h
    int w = tid >> 6;
    int lane = tid & 63;
    f32x4 acc[2][4];
#pragma unroll
    for (int i = 0; i < 2; ++i)
#pragma unroll
        for (int j = 0; j < 4; ++j) acc[i][j] = (f32x4){0.f, 0.f, 0.f, 0.f};

    int arow_lo = lane & 15;
    int akofs = (lane >> 4) * 8;
#pragma unroll
    for (int ks = 0; ks < 4; ++ks) {
        int kk = ks * 32 + akofs;
        int rr0 = (2 * w) * 16 + arow_lo;
        int rr1 = rr0 + 16;
        short8v a0 = *(const short8v*)(lds + ((rr0 * 256 + kk * 2) ^ ((rr0 & 7) << 4)));
        short8v a1 = *(const short8v*)(lds + ((rr1 * 256 + kk * 2) ^ ((rr1 & 7) << 4)));
#pragma unroll
        for (int ht = 0; ht < 4; ++ht) {
            short8v b = *(const short8v*)(lds + 32768 + (ht * 4 + ks) * 1024 + lane * 16);
            acc[0][ht] = __builtin_amdgcn_mfma_f32_16x16x32_bf16(a0, b, acc[0][ht], 0, 0, 0);
            acc[1][ht] = __builtin_amdgcn_mfma_f32_16x16x32_bf16(a1, b, acc[1][ht], 0, 0, 0);
        }
    }

    // ---- epilogue: int8 quantize from regs. D frag: col=lane&15, row=(lane>>4)*4+reg.
    // Row r's 64 h live in 16 lanes x 4 ht-regs. Byte colh*4+ht of row = h(ht*16+colh).
    {
        int colh = lane & 15;
        int rquad = lane >> 4;
#pragma unroll
        for (int rt = 0; rt < 2; ++rt)
#pragma unroll
            for (int reg = 0; reg < 4; ++reg) {
                float m = fmaxf(fmaxf(fabsf(acc[rt][0][reg]), fabsf(acc[rt][1][reg])),
                                fmaxf(fabsf(acc[rt][2][reg]), fabsf(acc[rt][3][reg])));
                m = fmaxf(m, __shfl_xor(m, 1));
                m = fmaxf(m, __shfl_xor(m, 2));
                m = fmaxf(m, __shfl_xor(m, 4));
                m = fmaxf(m, __shfl_xor(m, 8));
                m = fmaxf(m, 1e-20f);
                float inv = 127.0f / m;
                uint pk = 0;
#pragma unroll
                for (int ht = 0; ht < 4; ++ht) {
                    int q = __float2int_rn(acc[rt][ht][reg] * inv);
                    pk |= ((uint)q & 0xFFu) << (8 * ht);
                }
                int rl = (2 * w + rt) * 16 + rquad * 4 + reg;
                if (rbase0 + rl < nrows)
                    *(uint*)&pt[(size_t)(rbase0 + rl) * 64 + colh * 4] = pk;
                if (colh == 0) scaleLDS[rl] = m * (1.0f / 127.0f);
            }
    }

    __syncthreads();  // scaleLDS visible

    // ---- sums from LDS bf16 tile (2 threads per row) + stats write
    {
        int row = tid >> 1, half = tid & 1;
        float s = 0.f, q = 0.f;
#pragma unroll
        for (int i = 0; i < 8; ++i) {
            int byte = (row * 256 + half * 128 + i * 16) ^ ((row & 7) << 4);
            short8v v = *(const short8v*)(lds + byte);
#pragma unroll
            for (int j = 0; j < 8; ++j) {
                float x = bf2f((unsigned short)v[j]);
                s += x;
                q = fmaf(x, x, q);
            }
        }
        s += __shfl_xor(s, 1);
        q += __shfl_xor(q, 1);
        if (half == 0 && rbase0 + row < nrows)
            st[rbase0 + row] = make_float4(s, q, scaleLDS[row], 0.f);
    }
}

// ---------------- per-pair fused LN+MLP via int8 tables.
// 8 lanes per pair; lane l holds bytes 8l..8l+7 (one uint2), byte k -> h=(k&3)*16+(k>>2).
__global__ __launch_bounds__(256) void k_pairs(const int* __restrict__ node_idx,
                                               const int* __restrict__ edge_idx,
                                               const signed char* __restrict__ node_pt,
                                               const signed char* __restrict__ edge_pt,
                                               const float4* __restrict__ node_st,
                                               const float4* __restrict__ edge_st,
                                               const float* __restrict__ Gv,
                                               const float* __restrict__ Bv,
                                               const float* __restrict__ W2,
                                               const float* __restrict__ b2,
                                               float* __restrict__ out, int E) {
    int gtid = blockIdx.x * 256 + threadIdx.x;
    int l = gtid & 7;
    int grp = gtid >> 3;
    int ngrps = (gridDim.x * 256) >> 3;

    float G8[8], B8[8], W8[8];
#pragma unroll
    for (int j = 0; j < 8; ++j) {
        int k = l * 8 + j;
        int h = (k & 3) * 16 + (k >> 2);   // table byte permutation
        G8[j] = Gv[h];
        B8[j] = Bv[h];
        W8[j] = W2[h];
    }
    float b2v = b2[0];

#pragma unroll 4
    for (int p = grp; p < E; p += ngrps) {
        int ni = node_idx[p];
        int ei = edge_idx[p];
        uint2 qe2 = *(const uint2*)&edge_pt[(size_t)ei * 64 + l * 8];
        uint2 qn2 = *(const uint2*)&node_pt[(size_t)ni * 64 + l * 8];
        float4 se = edge_st[ei];
        float4 sn = node_st[ni];

        float S = se.x + sn.x;
        float Q = se.y + sn.y;
        float mu = S * (1.f / TWO_D);
        float var = fmaf(Q, 1.f / TWO_D, -mu * mu);
        float rstd = rsqrtf(var + LN_EPS);
        float nmu = -mu;
        float esc = se.z, nsc = sn.z;

        float acc = 0.f;
#pragma unroll
        for (int j = 0; j < 8; ++j) {
            uint we = (j < 4) ? qe2.x : qe2.y;
            uint wn = (j < 4) ? qn2.x : qn2.y;
            int qa = (int)(signed char)(we >> (8 * (j & 3)));
            int qb = (int)(signed char)(wn >> (8 * (j & 3)));
            float v = fmaf((float)qa, esc, (float)qb * nsc);
            float t = fmaf(nmu, G8[j], v);
            float hv = fmaf(rstd, t, B8[j]);
            hv = fmaxf(hv, 0.f);
            acc = fmaf(hv, W8[j], acc);
        }

        acc += __shfl_xor(acc, 1);
        acc += __shfl_xor(acc, 2);
        acc += __shfl_xor(acc, 4);

        if (l == 0) out[p] = acc + b2v;
    }
}

extern "C" void kernel_launch(void* const* d_in, const int* in_sizes, int n_in,
                              void* d_out, int out_size, void* d_ws, size_t ws_size,
                              hipStream_t stream) {
    const float* node_feat = (const float*)d_in[0];
    const float* edge_feat = (const float*)d_in[1];
    const float* gamma = (const float*)d_in[2];
    const float* beta = (const float*)d_in[3];
    const float* W1 = (const float*)d_in[4];
    const float* b1 = (const float*)d_in[5];
    const float* W2 = (const float*)d_in[6];
    const float* b2 = (const float*)d_in[7];
    const int* node_idx = (const int*)d_in[8];
    const int* edge_idx = (const int*)d_in[9];

    int n_nodes = in_sizes[0] / DD;
    int n_edges = in_sizes[1] / DD;
    int E = in_sizes[8];

    char* wsb = (char*)d_ws;
    size_t o = 0;
    float* GB = (float*)(wsb + o); o += 512;
    float4* node_st = (float4*)(wsb + o); o += (size_t)n_nodes * 16;
    float4* edge_st = (float4*)(wsb + o); o += (size_t)n_edges * 16;
    o = (o + 127) & ~(size_t)127;
    signed char* node_pt = (signed char*)(wsb + o); o += (size_t)n_nodes * 64;
    signed char* edge_pt = (signed char*)(wsb + o); o += (size_t)n_edges * 64;
    // total ws ~= 1.9 MB stats + 7.7 MB tables ~= 9.6 MB

    int nbN = (n_nodes + 127) / 128;
    int nbE = (n_edges + 127) / 128;

    k_fused<<<1 + nbN + nbE, 256, 0, stream>>>(node_feat, n_nodes, nbN,
                                               edge_feat, n_edges,
                                               gamma, beta, W1, b1,
                                               node_pt, node_st,
                                               edge_pt, edge_st, GB);
    k_pairs<<<2048, 256, 0, stream>>>(node_idx, edge_idx, node_pt, edge_pt,
                                      node_st, edge_st, GB, GB + 64, W2, b2,
                                      (float*)d_out, E);
}

// Round 9
// 52.407 us; speedup vs baseline: 1.3931x; 1.0372x over previous
//
#include <hip/hip_runtime.h>

#define LN_EPS 1e-5f
#define DD 128
#define TWO_D 256
#define HH 64
#define PPB 512   // pairs per block in k_pairs

typedef unsigned int uint;
typedef unsigned short ushort;
typedef __attribute__((ext_vector_type(8))) short short8v;   // 8 bf16 (4 VGPRs)
typedef __attribute__((ext_vector_type(4))) float f32x4;     // MFMA accumulator

__device__ __forceinline__ ushort f2bf(float f) {
    uint u = __float_as_uint(f);
    u += 0x7FFFu + ((u >> 16) & 1u);  // round-to-nearest-even
    return (ushort)(u >> 16);
}
__device__ __forceinline__ float bf2f(ushort h) {
    return __uint_as_float(((uint)h) << 16);
}

// ---------------- fused: block 0 = prep (G, B1c); blocks [1,nbN] = node proj;
// blocks (nbN, nbN+nbE] = edge proj. Each proj block: 128 rows via MFMA,
// output int8-quantized per row, h-permuted byte layout:
// table byte b of a row holds h = (b&3)*16 + (b>>2).
// stats[r] = uint2{ f32 S, bf16(Q)<<16 | bf16(scale) }
__global__ __launch_bounds__(256) void k_fused(
    const float* __restrict__ node_feat, int n_nodes, int nbN,
    const float* __restrict__ edge_feat, int n_edges,
    const float* __restrict__ gamma, const float* __restrict__ beta,
    const float* __restrict__ W1, const float* __restrict__ b1,
    signed char* __restrict__ node_pt, uint2* __restrict__ node_st,
    signed char* __restrict__ edge_pt, uint2* __restrict__ edge_st,
    float* __restrict__ GB) {
    int bid = blockIdx.x;
    int tid = threadIdx.x;

    if (bid == 0) {
        if (tid < 128) {
            int h = tid & 63;
            bool isB = tid >= 64;
            float acc = isB ? b1[h] : 0.f;
            const float* coef = isB ? beta : gamma;
#pragma unroll 8
            for (int d = 0; d < TWO_D; ++d)
                acc = fmaf(coef[d], W1[d * HH + h], acc);
            GB[tid] = acc;
        }
        return;
    }

    const float* feat;
    int nrows, gofs, rbase0;
    signed char* pt;
    uint2* st;
    if (bid <= nbN) {
        feat = node_feat; nrows = n_nodes; gofs = 128;
        rbase0 = (bid - 1) * 128; pt = node_pt; st = node_st;
    } else {
        feat = edge_feat; nrows = n_edges; gofs = 0;
        rbase0 = (bid - 1 - nbN) * 128; pt = edge_pt; st = edge_st;
    }

    // LDS: [0,32K) featA bf16 [128][128], byte=(r*256+k*2)^((r&7)<<4)
    //      [32K,48K) gwB packed MFMA-B frags
    //      [48K,48K+512) per-row scale
    __shared__ __align__(16) char lds[49664];
    float* scaleLDS = (float*)(lds + 49152);

    // ---- stage gwB in MFMA B-fragment order: B[k][h] = gamma[gofs+k]*W1[gofs+k][h]
    {
        int l = tid & 63;
        int w = tid >> 6;  // 0..3
#pragma unroll
        for (int ci = 0; ci < 4; ++ci) {
            int combo = ci * 4 + w;           // = ht*4 + ks
            int ks = combo & 3;
            int ht = combo >> 2;
            int kbase = gofs + ks * 32 + (l >> 4) * 8;
            int h = ht * 16 + (l & 15);
            short8v v;
#pragma unroll
            for (int j = 0; j < 8; ++j)
                v[j] = (short)f2bf(gamma[kbase + j] * W1[(size_t)(kbase + j) * HH + h]);
            *(short8v*)(lds + 32768 + combo * 1024 + l * 16) = v;
        }
    }

    // ---- stage featA: 64KB contiguous f32 -> bf16 LDS tile (burst of 16 dwordx4)
    {
        float4 tmp[16];
#pragma unroll
        for (int u = 0; u < 16; ++u) {
            int F4 = u * 256 + tid;        // float4 index within tile
            int r = F4 >> 5;               // 32 float4 per row
            int rg = rbase0 + r;
            rg = rg < nrows ? rg : (nrows - 1);
            int c4 = (F4 & 31) * 4;        // col in floats
            tmp[u] = *(const float4*)&feat[(size_t)rg * DD + c4];
        }
#pragma unroll
        for (int u = 0; u < 16; ++u) {
            int F4 = u * 256 + tid;
            int r = F4 >> 5;
            int c4 = (F4 & 31) * 4;
            uint2 wv;
            wv.x = (uint)f2bf(tmp[u].x) | ((uint)f2bf(tmp[u].y) << 16);
            wv.y = (uint)f2bf(tmp[u].z) | ((uint)f2bf(tmp[u].w) << 16);
            int byte = (r * 256 + c4 * 2) ^ ((r & 7) << 4);
            *(uint2*)(lds + byte) = wv;
        }
    }

    __syncthreads();

    // ---- MFMA: wave w computes rows [32w, 32w+32) x 64 h
    int w = tid >> 6;
    int lane = tid & 63;
    f32x4 acc[2][4];
#pragma unroll
    for (int i = 0; i < 2; ++i)
#pragma unroll
        for (int j = 0; j < 4; ++j) acc[i][j] = (f32x4){0.f, 0.f, 0.f, 0.f};

    int arow_lo = lane & 15;
    int akofs = (lane >> 4) * 8;
#pragma unroll
    for (int ks = 0; ks < 4; ++ks) {
        int kk = ks * 32 + akofs;
        int rr0 = (2 * w) * 16 + arow_lo;
        int rr1 = rr0 + 16;
        short8v a0 = *(const short8v*)(lds + ((rr0 * 256 + kk * 2) ^ ((rr0 & 7) << 4)));
        short8v a1 = *(const short8v*)(lds + ((rr1 * 256 + kk * 2) ^ ((rr1 & 7) << 4)));
#pragma unroll
        for (int ht = 0; ht < 4; ++ht) {
            short8v b = *(const short8v*)(lds + 32768 + (ht * 4 + ks) * 1024 + lane * 16);
            acc[0][ht] = __builtin_amdgcn_mfma_f32_16x16x32_bf16(a0, b, acc[0][ht], 0, 0, 0);
            acc[1][ht] = __builtin_amdgcn_mfma_f32_16x16x32_bf16(a1, b, acc[1][ht], 0, 0, 0);
        }
    }

    // ---- epilogue: int8 quantize from regs. D frag: col=lane&15, row=(lane>>4)*4+reg.
    {
        int colh = lane & 15;
        int rquad = lane >> 4;
#pragma unroll
        for (int rt = 0; rt < 2; ++rt)
#pragma unroll
            for (int reg = 0; reg < 4; ++reg) {
                float m = fmaxf(fmaxf(fabsf(acc[rt][0][reg]), fabsf(acc[rt][1][reg])),
                                fmaxf(fabsf(acc[rt][2][reg]), fabsf(acc[rt][3][reg])));
                m = fmaxf(m, __shfl_xor(m, 1));
                m = fmaxf(m, __shfl_xor(m, 2));
                m = fmaxf(m, __shfl_xor(m, 4));
                m = fmaxf(m, __shfl_xor(m, 8));
                m = fmaxf(m, 1e-20f);
                float inv = 127.0f / m;
                uint pk = 0;
#pragma unroll
                for (int ht = 0; ht < 4; ++ht) {
                    int q = __float2int_rn(acc[rt][ht][reg] * inv);
                    pk |= ((uint)q & 0xFFu) << (8 * ht);
                }
                int rl = (2 * w + rt) * 16 + rquad * 4 + reg;
                if (rbase0 + rl < nrows)
                    *(uint*)&pt[(size_t)(rbase0 + rl) * 64 + colh * 4] = pk;
                if (colh == 0) scaleLDS[rl] = m * (1.0f / 127.0f);
            }
    }

    __syncthreads();  // scaleLDS visible

    // ---- sums from LDS bf16 tile (2 threads per row) + packed stats write
    {
        int row = tid >> 1, half = tid & 1;
        float s = 0.f, q = 0.f;
#pragma unroll
        for (int i = 0; i < 8; ++i) {
            int byte = (row * 256 + half * 128 + i * 16) ^ ((row & 7) << 4);
            short8v v = *(const short8v*)(lds + byte);
#pragma unroll
            for (int j = 0; j < 8; ++j) {
                float x = bf2f((ushort)v[j]);
                s += x;
                q = fmaf(x, x, q);
            }
        }
        s += __shfl_xor(s, 1);
        q += __shfl_xor(q, 1);
        if (half == 0 && rbase0 + row < nrows) {
            uint packed = ((uint)f2bf(q) << 16) | (uint)f2bf(scaleLDS[row]);
            st[rbase0 + row] = make_uint2(__float_as_uint(s), packed);
        }
    }
}

// ---------------- per-pair fused LN+MLP via int8 tables.
// Block handles PPB contiguous pairs; idx staged in LDS first (kills the
// idx->gather dependent-latency chain). 8 lanes per pair; lane l holds
// bytes 8l..8l+7 (one uint2), byte k -> h=(k&3)*16+(k>>2).
__global__ __launch_bounds__(256) void k_pairs(const int* __restrict__ node_idx,
                                               const int* __restrict__ edge_idx,
                                               const signed char* __restrict__ node_pt,
                                               const signed char* __restrict__ edge_pt,
                                               const uint2* __restrict__ node_st,
                                               const uint2* __restrict__ edge_st,
                                               const float* __restrict__ Gv,
                                               const float* __restrict__ Bv,
                                               const float* __restrict__ W2,
                                               const float* __restrict__ b2,
                                               float* __restrict__ out, int E) {
    __shared__ int sNi[PPB];
    __shared__ int sEi[PPB];
    int tid = threadIdx.x;
    int base = blockIdx.x * PPB;
    int cnt = E - base;
    cnt = cnt < PPB ? cnt : PPB;
    for (int i = tid; i < cnt; i += 256) {
        sNi[i] = node_idx[base + i];
        sEi[i] = edge_idx[base + i];
    }
    __syncthreads();

    int l = tid & 7;
    int grp = tid >> 3;  // 32 groups/block

    float G8[8], B8[8], W8[8];
#pragma unroll
    for (int j = 0; j < 8; ++j) {
        int k = l * 8 + j;
        int h = (k & 3) * 16 + (k >> 2);   // table byte permutation
        G8[j] = Gv[h];
        B8[j] = Bv[h];
        W8[j] = W2[h];
    }
    float b2v = b2[0];

#pragma unroll 4
    for (int i = grp; i < cnt; i += 32) {
        int ni = sNi[i];
        int ei = sEi[i];
        uint2 qe2 = *(const uint2*)&edge_pt[(size_t)ei * 64 + l * 8];
        uint2 qn2 = *(const uint2*)&node_pt[(size_t)ni * 64 + l * 8];
        uint2 se = edge_st[ei];
        uint2 sn = node_st[ni];

        float S = __uint_as_float(se.x) + __uint_as_float(sn.x);
        float Q = bf2f((ushort)(se.y >> 16)) + bf2f((ushort)(sn.y >> 16));
        float esc = bf2f((ushort)(se.y & 0xFFFFu));
        float nsc = bf2f((ushort)(sn.y & 0xFFFFu));

        float mu = S * (1.f / TWO_D);
        float var = fmaf(Q, 1.f / TWO_D, -mu * mu);
        float rstd = rsqrtf(var + LN_EPS);
        float nmu = -mu;

        uint ue_[4] = {qe2.x, qe2.y, 0, 0};
        uint un_[4] = {qn2.x, qn2.y, 0, 0};
        float acc = 0.f;
#pragma unroll
        for (int j = 0; j < 8; ++j) {
            uint we = (j < 4) ? ue_[0] : ue_[1];
            uint wn = (j < 4) ? un_[0] : un_[1];
            int qa = (int)(signed char)(we >> (8 * (j & 3)));
            int qb = (int)(signed char)(wn >> (8 * (j & 3)));
            float v = fmaf((float)qa, esc, (float)qb * nsc);
            float t = fmaf(nmu, G8[j], v);
            float hv = fmaf(rstd, t, B8[j]);
            hv = fmaxf(hv, 0.f);
            acc = fmaf(hv, W8[j], acc);
        }

        acc += __shfl_xor(acc, 1);
        acc += __shfl_xor(acc, 2);
        acc += __shfl_xor(acc, 4);

        if (l == 0) out[base + i] = acc + b2v;
    }
}

extern "C" void kernel_launch(void* const* d_in, const int* in_sizes, int n_in,
                              void* d_out, int out_size, void* d_ws, size_t ws_size,
                              hipStream_t stream) {
    const float* node_feat = (const float*)d_in[0];
    const float* edge_feat = (const float*)d_in[1];
    const float* gamma = (const float*)d_in[2];
    const float* beta = (const float*)d_in[3];
    const float* W1 = (const float*)d_in[4];
    const float* b1 = (const float*)d_in[5];
    const float* W2 = (const float*)d_in[6];
    const float* b2 = (const float*)d_in[7];
    const int* node_idx = (const int*)d_in[8];
    const int* edge_idx = (const int*)d_in[9];

    int n_nodes = in_sizes[0] / DD;
    int n_edges = in_sizes[1] / DD;
    int E = in_sizes[8];

    char* wsb = (char*)d_ws;
    size_t o = 0;
    float* GB = (float*)(wsb + o); o += 512;
    uint2* node_st = (uint2*)(wsb + o); o += (size_t)n_nodes * 8;
    uint2* edge_st = (uint2*)(wsb + o); o += (size_t)n_edges * 8;
    o = (o + 127) & ~(size_t)127;
    signed char* node_pt = (signed char*)(wsb + o); o += (size_t)n_nodes * 64;
    signed char* edge_pt = (signed char*)(wsb + o); o += (size_t)n_edges * 64;
    // total ws ~= 0.96 MB stats + 7.7 MB tables ~= 8.7 MB

    int nbN = (n_nodes + 127) / 128;
    int nbE = (n_edges + 127) / 128;

    k_fused<<<1 + nbN + nbE, 256, 0, stream>>>(node_feat, n_nodes, nbN,
                                               edge_feat, n_edges,
                                               gamma, beta, W1, b1,
                                               node_pt, node_st,
                                               edge_pt, edge_st, GB);
    k_pairs<<<(E + PPB - 1) / PPB, 256, 0, stream>>>(node_idx, edge_idx, node_pt, edge_pt,
                                                     node_st, edge_st, GB, GB + 64, W2, b2,
                                                     (float*)d_out, E);
}